// Round 4
// baseline (1472.902 us; speedup 1.0000x reference)
//
#include <hip/hip_runtime.h>

// Problem constants (match reference setup_inputs)
#define NN 50000
#define EE 800000
#define DD 256
#define LL 3
#define GG 512
#define MPAD 50048   // 782 * 64, GEMM row-tile padding
#define TILES 782    // MPAD/64 mlp tiles per layer

typedef __attribute__((ext_vector_type(4))) _Float16 half4;
typedef __attribute__((ext_vector_type(8))) _Float16 half8;
typedef __attribute__((ext_vector_type(16))) float floatx16;

// ---------------------------------------------------------------------------
// Fused prep kernel (independent work, split by blockIdx range):
//   [0, 12500)        : x fp32 -> fp16 convert
//   [12500, 12692)    : weight pack (192 blocks)
//   [12692, 15817)    : degree histogram (3125 blocks)
// ---------------------------------------------------------------------------
#define CONV_B 12500
#define WPK_B  192
#define HIST_B 3125

__global__ void k_prep(const float* __restrict__ x, _Float16* __restrict__ h16,
                       const float* __restrict__ Ws1, const float* __restrict__ Ws2,
                       _Float16* __restrict__ Wp,
                       const int* __restrict__ dst, int* __restrict__ deg) {
    int b = blockIdx.x;
    if (b < CONV_B) {
        int i = b * 256 + threadIdx.x;  // float4 groups, NN*DD/4 = 3.2M
        if (i >= NN * DD / 4) return;
        float4 v = ((const float4*)x)[i];
        half4 o;
        o.x = (_Float16)v.x; o.y = (_Float16)v.y; o.z = (_Float16)v.z; o.w = (_Float16)v.w;
        ((half4*)h16)[i] = o;
    } else if (b < CONV_B + WPK_B) {
        // Pre-pack W (fp32 [256,256], k-major) into fp16 MFMA B-fragments for
        // mfma_f32_32x32x16_f16. Fragment (ks,nt): lane l holds
        // B[ks*16 + (l>>5)*8 + j][nt*32 + (l&31)], j=0..7.
        int tid  = (b - CONV_B) * 256 + threadIdx.x;  // 6*16*8*64 = 49152
        int lane = tid & 63;
        int nt   = (tid >> 6) & 7;
        int ks   = (tid >> 9) & 15;
        int w    = tid >> 13;
        if (w >= 6) return;
        int l = w >> 1, s = w & 1;
        const float* W = (s == 0 ? Ws1 : Ws2) + (size_t)l * DD * DD;
        int kbase = ks * 16 + (lane >> 5) * 8;
        int n     = nt * 32 + (lane & 31);
        half8 hi;
#pragma unroll
        for (int j = 0; j < 8; ++j) hi[j] = (_Float16)W[(size_t)(kbase + j) * DD + n];
        ((half8*)Wp)[(((size_t)w * 16 + ks) * 8 + nt) * 64 + lane] = hi;
    } else {
        int i = (b - CONV_B - WPK_B) * 256 + threadIdx.x;
        if (i < EE) atomicAdd(&deg[dst[i]], 1);
    }
}

// ---------------------------------------------------------------------------
// CSR build: 3-kernel parallel scan -> scatter (histogram is in k_prep)
// ---------------------------------------------------------------------------
__global__ void k_scan1(const int* __restrict__ deg, int* __restrict__ rp,
                        int* __restrict__ bsum, int n) {
    __shared__ int s[1024];
    int t = threadIdx.x;
    int i = blockIdx.x * 1024 + t;
    int v = (i < n) ? deg[i] : 0;
    s[t] = v;
    __syncthreads();
    for (int off = 1; off < 1024; off <<= 1) {
        int tmp = (t >= off) ? s[t - off] : 0;
        __syncthreads();
        s[t] += tmp;
        __syncthreads();
    }
    if (i < n) rp[i] = s[t] - v;          // local exclusive
    if (t == 1023) bsum[blockIdx.x] = s[1023];
}

__global__ void k_scan2(int* __restrict__ bsum, int nb, int* __restrict__ total_out) {
    int lane = threadIdx.x & 63;
    int v = (lane < nb) ? bsum[lane] : 0;
    int orig = v;
    for (int off = 1; off < 64; off <<= 1) {
        int u = __shfl_up(v, off);
        if (lane >= off) v += u;
    }
    if (lane < nb) bsum[lane] = v - orig;  // exclusive block offsets
    if (lane == 63) *total_out = v;        // grand total -> row_ptr[N]
}

__global__ void k_scan3(int* __restrict__ rp, const int* __restrict__ bsum,
                        int* __restrict__ cursor, int n) {
    int i = blockIdx.x * 1024 + threadIdx.x;
    if (i < n) {
        int v = rp[i] + bsum[blockIdx.x];
        rp[i] = v;
        cursor[i] = v;
    }
}

__global__ void k_scatter(const int* __restrict__ src, const int* __restrict__ dst,
                          int* __restrict__ cursor, int* __restrict__ csr_src, int e) {
    int i = blockIdx.x * blockDim.x + threadIdx.x;
    if (i < e) {
        int d = dst[i];
        int pos = atomicAdd(&cursor[d], 1);
        csr_src[pos] = src[i];
    }
}

// ---------------------------------------------------------------------------
// Fused per-layer pipeline kernel: gather producers + MLP consumers.
// Grid = TILES * 17 blocks of 256 threads. Group g = blockIdx/17 owns output
// rows [64g, 64g+64). Sub-blocks 0..15 each gather 4 nodes (agg = h + sum of
// neighbor rows) and write agg via agent-scope (write-through) stores, then
// bump flags[g]. Sub-block 16 spins until flags[g]==16 (producers placed
// immediately before it in dispatch order -> short spin), acquires, then runs
// the 2-GEMM MLP + pool accumulate on those 64 rows.
// Deadlock-free by counting: <=782 consumers < resident capacity (5 blk/CU
// x 256 CU), producers never wait.
// LDS: exactly 32 KB, time-shared (eidx/rp_s | t_lds | batch cache).
// ---------------------------------------------------------------------------
__global__ __launch_bounds__(256) void k_layer(
        const _Float16* __restrict__ h,    // layer input [MPAD, 256]
        const int* __restrict__ row_ptr,
        const int* __restrict__ csr_src,
        const int* __restrict__ batch,
        const _Float16* __restrict__ Wp1, const float* __restrict__ b1,
        const _Float16* __restrict__ Wp2, const float* __restrict__ b2,
        _Float16* __restrict__ agg,        // agg16 [MPAD, 256]
        _Float16* __restrict__ Hout,       // layer output [MPAD, 256] (!= h)
        float* __restrict__ Fout,          // node_embed + l*256, row stride 768
        float* __restrict__ Gout,          // gsum + l*256, row stride 768
        int* __restrict__ flags) {         // [TILES], zeroed
    __shared__ _Float16 t_lds[64 * 256];   // 32 KB, multi-purpose
    int t    = threadIdx.x;
    int lane = t & 63;
    int w    = t >> 6;
    int grp  = blockIdx.x / 17;
    int sub  = blockIdx.x % 17;

    if (sub < 16) {
        // ================= gather role: 4 nodes =================
        int* eidx = (int*)t_lds;        // 1024 ints
        int* rp_s = eidx + 1024;        // 5 ints
        int n0 = grp * 64 + sub * 4;
        if (t < 5) {
            int nn = n0 + t;
            if (nn > NN) nn = NN;
            rp_s[t] = row_ptr[nn];
        }
        __syncthreads();
        int beg0 = rp_s[0];
        int cnt  = rp_s[4] - beg0;
        for (int i = t; i < cnt && i < 1024; i += 256) eidx[i] = csr_src[beg0 + i];
        __syncthreads();

        int n = n0 + w;
        if (n < NN) {
            int beg = rp_s[w] - beg0, end = rp_s[w + 1] - beg0;
            int hf = lane >> 5;   // 0: own row + even edges; 1: odd edges
            int cl = lane & 31;   // column group: cols [cl*8, cl*8+8)
            const half8* hp = (const half8*)h;

            half8 acc;
#pragma unroll
            for (int i = 0; i < 8; ++i) acc[i] = (_Float16)0;
            if (hf == 0) acc = hp[(size_t)n * 32 + cl];

            if (cnt <= 1024) {
                int k = beg;
                for (; k + 16 <= end; k += 16) {
                    half8 v[8];
#pragma unroll
                    for (int u = 0; u < 8; ++u) {
                        int s = eidx[k + 2 * u + hf];
                        v[u] = hp[(size_t)s * 32 + cl];
                    }
#pragma unroll
                    for (int u = 0; u < 8; ++u) acc += v[u];
                }
                if (k < end) {  // tail < 16 edges: predicated, all in flight
#pragma unroll
                    for (int u = 0; u < 8; ++u) {
                        int e = k + 2 * u + hf;
                        half8 v;
#pragma unroll
                        for (int i = 0; i < 8; ++i) v[i] = (_Float16)0;
                        if (e < end) v = hp[(size_t)eidx[e] * 32 + cl];
                        acc += v;
                    }
                }
            } else {
                // rare fallback: indices from global
                int k = beg;
                for (; k + 16 <= end; k += 16) {
                    half8 v[8];
#pragma unroll
                    for (int u = 0; u < 8; ++u) {
                        int s = csr_src[beg0 + k + 2 * u + hf];
                        v[u] = hp[(size_t)s * 32 + cl];
                    }
#pragma unroll
                    for (int u = 0; u < 8; ++u) acc += v[u];
                }
                if (k < end) {
#pragma unroll
                    for (int u = 0; u < 8; ++u) {
                        int e = k + 2 * u + hf;
                        half8 v;
#pragma unroll
                        for (int i = 0; i < 8; ++i) v[i] = (_Float16)0;
                        if (e < end) v = hp[(size_t)csr_src[beg0 + e] * 32 + cl];
                        acc += v;
                    }
                }
            }

            // fold odd-half into even-half (16 B via 4 shfl_xor)
            int4 ai = *(int4*)&acc;
            int4 bi;
            bi.x = __shfl_xor(ai.x, 32);
            bi.y = __shfl_xor(ai.y, 32);
            bi.z = __shfl_xor(ai.z, 32);
            bi.w = __shfl_xor(ai.w, 32);
            acc += *(half8*)&bi;
            if (hf == 0) {
                // agent-scope stores: write through the (non-coherent) L2 so
                // the consumer tile (possibly another XCD) sees the data.
                unsigned long long uu[2];
                __builtin_memcpy(uu, &acc, 16);
                unsigned long long* p =
                    (unsigned long long*)(agg + (size_t)n * DD) + (size_t)cl * 2;
                __hip_atomic_store(p,     uu[0], __ATOMIC_RELAXED, __HIP_MEMORY_SCOPE_AGENT);
                __hip_atomic_store(p + 1, uu[1], __ATOMIC_RELAXED, __HIP_MEMORY_SCOPE_AGENT);
            }
        }
        __syncthreads();  // drains vmcnt(0): all 4 rows' stores are visible
        if (t == 0)
            __hip_atomic_fetch_add(&flags[grp], 1, __ATOMIC_RELAXED, __HIP_MEMORY_SCOPE_AGENT);
        return;
    }

    // ================= mlp role: 64-row tile =================
    if (t == 0) {
        while (__hip_atomic_load(&flags[grp], __ATOMIC_RELAXED, __HIP_MEMORY_SCOPE_AGENT) < 16)
            __builtin_amdgcn_s_sleep(2);
    }
    __syncthreads();
    // acquire: invalidate stale cache lines before reading agg
    (void)__hip_atomic_load(&flags[grp], __ATOMIC_ACQUIRE, __HIP_MEMORY_SCOPE_AGENT);

    int wm = (w >> 1) & 1, wn = w & 1;
    int r0 = grp * 64;

    // ---- GEMM1: acc = agg @ W1 (A fragments direct from global) ----
    int arow = r0 + wm * 32 + (lane & 31);
    const half8* baseA = (const half8*)(agg + (size_t)arow * DD) + (lane >> 5);
    const half8* B1    = (const half8*)Wp1;

    floatx16 acc[4];
#pragma unroll
    for (int nt = 0; nt < 4; ++nt)
#pragma unroll
        for (int i = 0; i < 16; ++i) acc[nt][i] = 0.0f;

#pragma unroll 4
    for (int ks = 0; ks < 16; ++ks) {
        half8 a = baseA[ks * 2];
#pragma unroll
        for (int nt = 0; nt < 4; ++nt) {
            half8 b = B1[(size_t)(ks * 8 + wn * 4 + nt) * 64 + lane];
            acc[nt] = __builtin_amdgcn_mfma_f32_32x32x16_f16(a, b, acc[nt], 0, 0, 0);
        }
    }

    // ---- epilogue 1: t = relu(acc + b1) -> LDS (fp16, swizzled) ----
#pragma unroll
    for (int nt = 0; nt < 4; ++nt) {
        int c  = wn * 128 + nt * 32 + (lane & 31);
        float bv = b1[c];
#pragma unroll
        for (int reg = 0; reg < 16; ++reg) {
            int lr = wm * 32 + (reg & 3) + 8 * (reg >> 2) + 4 * (lane >> 5);
            float v = fmaxf(acc[nt][reg] + bv, 0.0f);
            t_lds[lr * 256 + ((((c >> 3) ^ (lr & 7)) << 3) | (c & 7))] = (_Float16)v;
        }
    }
    __syncthreads();

    // ---- GEMM2: acc2 = t @ W2 (A fragments from swizzled LDS) ----
    const half8* B2 = (const half8*)Wp2;
    int r = wm * 32 + (lane & 31);
    floatx16 acc2[4];
#pragma unroll
    for (int nt = 0; nt < 4; ++nt)
#pragma unroll
        for (int i = 0; i < 16; ++i) acc2[nt][i] = 0.0f;

#pragma unroll 4
    for (int ks = 0; ks < 16; ++ks) {
        int kblk = ks * 2 + (lane >> 5);
        half8 a = *(const half8*)&t_lds[r * 256 + ((kblk ^ (r & 7)) << 3)];
#pragma unroll
        for (int nt = 0; nt < 4; ++nt) {
            half8 b = B2[(size_t)(ks * 8 + wn * 4 + nt) * 64 + lane];
            acc2[nt] = __builtin_amdgcn_mfma_f32_32x32x16_f16(a, b, acc2[nt], 0, 0, 0);
        }
    }

    // ---- stage batch ids into (now dead) t_lds for the pool phase ----
    __syncthreads();
    int* bs = (int*)t_lds;
    if (t < 64) {
        int row = r0 + t;
        bs[t] = (row < NN) ? batch[row] : 0x7fffffff;
    }
    __syncthreads();

    // ---- epilogue 2: h = relu(acc2 + b2) -> fp16 Hout + fp32 node_embed ----
    const int rbase = wm * 32 + 4 * (lane >> 5);
#pragma unroll
    for (int nt = 0; nt < 4; ++nt) {
        int col = wn * 128 + nt * 32 + (lane & 31);
        float bv = b2[col];
#pragma unroll
        for (int reg = 0; reg < 16; ++reg) {
            int rowid = rbase + (reg & 3) + 8 * (reg >> 2);
            int row = r0 + rowid;
            if (row < NN) {
                float v = fmaxf(acc2[nt][reg] + bv, 0.0f);
                Hout[(size_t)row * DD + col] = (_Float16)v;
                __builtin_nontemporal_store(v, &Fout[(size_t)row * 768 + col]);
            }
        }
    }

    // ---- pool accumulate: per-graph column sums (batch sorted; a wave's
    //      32 rows span 1-2 graphs). Cross-half merge by shfl_xor(32),
    //      then one atomicAdd per (graph, col) partial.
    int lastid = NN - 1 - r0 - wm * 32;
    if (lastid >= 0) {
        if (lastid > 31) lastid = 31;
        int g0 = bs[wm * 32];
        int g1 = bs[wm * 32 + lastid];
        for (int g = g0; g <= g1; ++g) {
#pragma unroll
            for (int nt = 0; nt < 4; ++nt) {
                int col = wn * 128 + nt * 32 + (lane & 31);
                float bv = b2[col];
                float s = 0.0f;
#pragma unroll
                for (int reg = 0; reg < 16; ++reg) {
                    int rowid = rbase + (reg & 3) + 8 * (reg >> 2);
                    if (bs[rowid] == g)
                        s += fmaxf(acc2[nt][reg] + bv, 0.0f);
                }
                s += __shfl_xor(s, 32);
                if (lane < 32)
                    atomicAdd(&Gout[(size_t)g * 768 + col], s);
            }
        }
    }
}

// ---------------------------------------------------------------------------
// Finalize pool: graph_embed = gsum / count. One block per graph.
// ---------------------------------------------------------------------------
__global__ void k_pool_final(const float* __restrict__ gsum,
                             const int* __restrict__ batch,
                             float* __restrict__ graph_embed) {
    int g = blockIdx.x;
    int t = threadIdx.x;  // 0..191
    int start, end;
    { int l = 0, h = NN; while (l < h) { int m = (l + h) >> 1; if (batch[m] < g) l = m + 1; else h = m; } start = l; }
    { int l = 0, h = NN; while (l < h) { int m = (l + h) >> 1; if (batch[m] < g + 1) l = m + 1; else h = m; } end = l; }
    int cnt = end - start;
    float inv = 1.0f / (float)(cnt > 0 ? cnt : 1);
    float4 v = ((const float4*)(gsum + (size_t)g * 768))[t];
    float4 o; o.x = v.x * inv; o.y = v.y * inv; o.z = v.z * inv; o.w = v.w * inv;
    ((float4*)(graph_embed + (size_t)g * 768))[t] = o;
}

// ---------------------------------------------------------------------------
extern "C" void kernel_launch(void* const* d_in, const int* in_sizes, int n_in,
                              void* d_out, int out_size, void* d_ws, size_t ws_size,
                              hipStream_t stream) {
    const float* x     = (const float*)d_in[0];  // [N, 256]
    const int*   ei    = (const int*)d_in[1];    // [2, E]
    const int*   batch = (const int*)d_in[2];    // [N] (sorted)
    const float* Ws1   = (const float*)d_in[3];  // [L, 256, 256]
    const float* bs1   = (const float*)d_in[4];  // [L, 256]
    const float* Ws2   = (const float*)d_in[5];  // [L, 256, 256]
    const float* bs2   = (const float*)d_in[6];  // [L, 256]

    float* out         = (float*)d_out;
    float* graph_embed = out;                     // [G, 768]
    float* node_embed  = out + (size_t)GG * 768;  // [N, 768]

    // Workspace (re-poisoned before every call; fully rebuilt here).
    // h double-buffered: k_layer reads h(l-1) while writing h(l).
    _Float16* h16   = (_Float16*)d_ws;                  // [MPAD, 256]
    _Float16* h_alt = h16 + (size_t)MPAD * DD;          // [MPAD, 256]
    _Float16* agg16 = h_alt + (size_t)MPAD * DD;        // [MPAD, 256]
    _Float16* Wp    = agg16 + (size_t)MPAD * DD;        // 6 * 65536 halfs
    float* gsum     = (float*)(Wp + (size_t)6 * 65536); // [G, 768]   (zeroed)
    int* flags      = (int*)(gsum + (size_t)GG * 768);  // [3*TILES]  (zeroed)
    int* cursor     = flags + 3 * TILES;                // [N]        (zeroed)
    int* bsum       = cursor + NN;                      // [64]       (zeroed)
    int* csr_src    = bsum + 64;                        // [E]
    int* row_ptr    = csr_src + EE;                     // [N+1]

    const int* src = ei;       // edge_index[0]
    const int* dst = ei + EE;  // edge_index[1]

    const int NB = (NN + 1023) / 1024;  // 49 scan blocks

    // Zero gsum + flags + cursor + bsum in one contiguous memset
    hipMemsetAsync(gsum, 0,
                   (size_t)GG * 768 * 4 + (size_t)3 * TILES * 4 +
                   (size_t)NN * 4 + 64 * 4, stream);

    // convert + wpack + hist in one launch
    k_prep<<<CONV_B + WPK_B + HIST_B, 256, 0, stream>>>(x, h16, Ws1, Ws2, Wp, dst, cursor);

    // Finish CSR (dst -> list of src)
    k_scan1<<<NB, 1024, 0, stream>>>(cursor, row_ptr, bsum, NN);
    k_scan2<<<1, 64, 0, stream>>>(bsum, NB, row_ptr + NN);
    k_scan3<<<NB, 1024, 0, stream>>>(row_ptr, bsum, cursor, NN);
    k_scatter<<<(EE + 255) / 256, 256, 0, stream>>>(src, dst, cursor, csr_src, EE);

    for (int l = 0; l < LL; ++l) {
        const _Float16* hin  = (l & 1) ? h_alt : h16;
        _Float16*       hout = (l & 1) ? h16 : h_alt;
        // pipelined gather + MLP + pool partials, one kernel per layer
        k_layer<<<TILES * 17, 256, 0, stream>>>(
            hin, row_ptr, csr_src, batch,
            Wp + (size_t)(2 * l + 0) * 65536, bs1 + (size_t)l * DD,
            Wp + (size_t)(2 * l + 1) * 65536, bs2 + (size_t)l * DD,
            agg16, hout, node_embed + (size_t)l * DD, gsum + (size_t)l * DD,
            flags + (size_t)l * TILES);
    }

    k_pool_final<<<GG, 192, 0, stream>>>(gsum, batch, graph_embed);
}

// Round 5
// 809.163 us; speedup vs baseline: 1.8203x; 1.8203x over previous
//
#include <hip/hip_runtime.h>

// Problem constants (match reference setup_inputs)
#define NN 50000
#define EE 800000
#define DD 256
#define LL 3
#define GG 512
#define MPAD 50048   // 782 * 64, GEMM row-tile padding
#define NSH 8        // column shards (one per XCD); 32 cols = 64 B per shard

typedef __attribute__((ext_vector_type(4))) _Float16 half4;
typedef __attribute__((ext_vector_type(8))) _Float16 half8;
typedef __attribute__((ext_vector_type(16))) float floatx16;
typedef __attribute__((ext_vector_type(4))) int int4v;

// h / agg live in SHARD-MAJOR layout: [shard][MPAD][32] halfs.
// Shard s holds columns [32s, 32s+32). One shard = 3.2 MB < 4 MB XCD L2.

// ---------------------------------------------------------------------------
// Fused prep kernel (independent work, split by blockIdx range):
//   [0, 12500)        : x fp32 -> fp16 convert (into shard-major h)
//   [12500, 12692)    : weight pack (192 blocks)
//   [12692, 15817)    : degree histogram (3125 blocks)
// ---------------------------------------------------------------------------
#define CONV_B 12500
#define WPK_B  192
#define HIST_B 3125

__global__ void k_prep(const float* __restrict__ x, _Float16* __restrict__ h16,
                       const float* __restrict__ Ws1, const float* __restrict__ Ws2,
                       _Float16* __restrict__ Wp,
                       const int* __restrict__ dst, int* __restrict__ deg) {
    int b = blockIdx.x;
    if (b < CONV_B) {
        int i = b * 256 + threadIdx.x;  // float4 groups, NN*64 total
        if (i >= NN * 64) return;
        float4 v = ((const float4*)x)[i];
        half4 o;
        o.x = (_Float16)v.x; o.y = (_Float16)v.y; o.z = (_Float16)v.z; o.w = (_Float16)v.w;
        int r = i >> 6, c4g = i & 63;       // 64 4-col groups per row
        int shard = c4g >> 3, within = c4g & 7;  // 8 groups per 32-col shard
        ((half4*)h16)[((size_t)shard * MPAD + r) * 8 + within] = o;
    } else if (b < CONV_B + WPK_B) {
        // Pre-pack W (fp32 [256,256], k-major) into fp16 MFMA B-fragments for
        // mfma_f32_32x32x16_f16. Fragment (ks,nt): lane l holds
        // B[ks*16 + (l>>5)*8 + j][nt*32 + (l&31)], j=0..7.
        int tid  = (b - CONV_B) * 256 + threadIdx.x;  // 6*16*8*64 = 49152
        int lane = tid & 63;
        int nt   = (tid >> 6) & 7;
        int ks   = (tid >> 9) & 15;
        int w    = tid >> 13;
        if (w >= 6) return;
        int l = w >> 1, s = w & 1;
        const float* W = (s == 0 ? Ws1 : Ws2) + (size_t)l * DD * DD;
        int kbase = ks * 16 + (lane >> 5) * 8;
        int n     = nt * 32 + (lane & 31);
        half8 hi;
#pragma unroll
        for (int j = 0; j < 8; ++j) hi[j] = (_Float16)W[(size_t)(kbase + j) * DD + n];
        ((half8*)Wp)[(((size_t)w * 16 + ks) * 8 + nt) * 64 + lane] = hi;
    } else {
        int i = (b - CONV_B - WPK_B) * 256 + threadIdx.x;
        if (i < EE) atomicAdd(&deg[dst[i]], 1);
    }
}

// ---------------------------------------------------------------------------
// CSR build: 3-kernel parallel scan -> scatter (histogram is in k_prep)
// ---------------------------------------------------------------------------
__global__ void k_scan1(const int* __restrict__ deg, int* __restrict__ rp,
                        int* __restrict__ bsum, int n) {
    __shared__ int s[1024];
    int t = threadIdx.x;
    int i = blockIdx.x * 1024 + t;
    int v = (i < n) ? deg[i] : 0;
    s[t] = v;
    __syncthreads();
    for (int off = 1; off < 1024; off <<= 1) {
        int tmp = (t >= off) ? s[t - off] : 0;
        __syncthreads();
        s[t] += tmp;
        __syncthreads();
    }
    if (i < n) rp[i] = s[t] - v;          // local exclusive
    if (t == 1023) bsum[blockIdx.x] = s[1023];
}

__global__ void k_scan2(int* __restrict__ bsum, int nb, int* __restrict__ total_out) {
    int lane = threadIdx.x & 63;
    int v = (lane < nb) ? bsum[lane] : 0;
    int orig = v;
    for (int off = 1; off < 64; off <<= 1) {
        int u = __shfl_up(v, off);
        if (lane >= off) v += u;
    }
    if (lane < nb) bsum[lane] = v - orig;  // exclusive block offsets
    if (lane == 63) *total_out = v;        // grand total -> row_ptr[N]
}

__global__ void k_scan3(int* __restrict__ rp, const int* __restrict__ bsum,
                        int* __restrict__ cursor, int n) {
    int i = blockIdx.x * 1024 + threadIdx.x;
    if (i < n) {
        int v = rp[i] + bsum[blockIdx.x];
        rp[i] = v;
        cursor[i] = v;
    }
}

__global__ void k_scatter(const int* __restrict__ src, const int* __restrict__ dst,
                          int* __restrict__ cursor, int* __restrict__ csr_src, int e) {
    int i = blockIdx.x * blockDim.x + threadIdx.x;
    if (i < e) {
        int d = dst[i];
        int pos = atomicAdd(&cursor[d], 1);
        csr_src[pos] = src[i];
    }
}

// ---------------------------------------------------------------------------
// XCD-sharded aggregation: agg[n] = h[n] + sum_{j->n} h[j], shard-major.
// Grid = 12500 node-groups x 8 shards; shard = blockIdx & 7, so consecutive
// blocks round-robin across XCDs and shard k's blocks land on XCD k. Each
// shard's h slice (3.2 MB) then stays resident in that XCD's 4 MB L2 for the
// whole kernel (~16x reuse per line, ~94% L2 hit vs ~50% unsharded).
// L2-residency protection: csr_src read nontemporal (no allocate), agg
// written nontemporal (no allocate). h reads are the ONLY cached stream.
// Wave layout: 16 edge-slots x 4 lanes x half8 (16 B) = full 64 B shard row
// per edge, 1 KB per load instruction. Two batches (32 edges) in flight.
// Cross-slot reduce: 4 rounds of shfl_xor (4/8/16/32); lanes 0-3 store.
// If the XCD round-robin assumption fails, blocks merely cache foreign
// shards -> perf degrades toward the unsharded case, never below it.
// ---------------------------------------------------------------------------
__global__ __launch_bounds__(256) void k_gather(
        const _Float16* __restrict__ h,
        const int* __restrict__ row_ptr,
        const int* __restrict__ csr_src,
        _Float16* __restrict__ agg) {
    int t = threadIdx.x, lane = t & 63, w = t >> 6;
    int shard = blockIdx.x & 7;
    int n = (blockIdx.x >> 3) * 4 + w;
    if (n >= NN) return;
    int beg = row_ptr[n], end = row_ptr[n + 1];
    int slot = lane >> 2, part = lane & 3;
    const half8* hp8 = (const half8*)h;
    size_t sbase = (size_t)shard * MPAD;

    half8 acc;
#pragma unroll
    for (int i = 0; i < 8; ++i) acc[i] = (_Float16)0;
    if (slot == 0) acc = hp8[(sbase + n) * 4 + part];   // self row

    for (int k = beg; k < end; k += 32) {
        int e0 = k + slot, e1 = k + 16 + slot;
        half8 v0, v1;
#pragma unroll
        for (int i = 0; i < 8; ++i) { v0[i] = (_Float16)0; v1[i] = (_Float16)0; }
        if (e0 < end) {
            int s = __builtin_nontemporal_load(&csr_src[e0]);
            v0 = hp8[(sbase + s) * 4 + part];
        }
        if (e1 < end) {
            int s = __builtin_nontemporal_load(&csr_src[e1]);
            v1 = hp8[(sbase + s) * 4 + part];
        }
        acc += v0; acc += v1;
    }

    // reduce across the 16 slots (lane bits 2..5)
#pragma unroll
    for (int m = 4; m < 64; m <<= 1) {
        int4v a = *(int4v*)&acc, b;
        b[0] = __shfl_xor(a[0], m);
        b[1] = __shfl_xor(a[1], m);
        b[2] = __shfl_xor(a[2], m);
        b[3] = __shfl_xor(a[3], m);
        acc += *(half8*)&b;
    }
    if (slot == 0)
        __builtin_nontemporal_store(*(int4v*)&acc,
                                    (int4v*)agg + (sbase + n) * 4 + part);
}

// ---------------------------------------------------------------------------
// Fused MLP + pool-accumulate: h_out = relu(relu(A@W1+b1)@W2+b2).
// Block: 256 threads = 4 waves, 64-row x 256-col tile; wave (wm,wn) owns the
// 32-row x 128-col quadrant (4 n-tiles of mfma_f32_32x32x16_f16).
// A (agg, shard-major) read nontemporal direct from global; t round-trips
// through LDS fp16 with XOR swizzle. Hout (shard-major, for next gather) and
// Fout (node_embed) written nontemporal -- single-use streams, keep L2 clean.
// Hout == nullptr on the last layer (never read).
// ---------------------------------------------------------------------------
__global__ __launch_bounds__(256) void k_mlp(
        const _Float16* __restrict__ A,    // agg16 shard-major
        const int* __restrict__ batch,
        const _Float16* __restrict__ Wp1, const float* __restrict__ b1,
        const _Float16* __restrict__ Wp2, const float* __restrict__ b2,
        _Float16* __restrict__ Hout,       // h16 shard-major (or nullptr)
        float* __restrict__ Fout,          // node_embed + l*256, row stride 768
        float* __restrict__ Gout) {        // gsum + l*256, row stride 768
    __shared__ _Float16 t_lds[64 * 256];   // 32 KB
    __shared__ int batch_s[64];
    int t    = threadIdx.x;
    int lane = t & 63;
    int w    = t >> 6;
    int wm   = w >> 1, wn = w & 1;
    int r0   = blockIdx.x * 64;

    if (t < 64) {
        int r = r0 + t;
        batch_s[t] = (r < NN) ? batch[r] : 0x7fffffff;
    }

    // ---- GEMM1: acc = A @ W1 (A fragments nt from shard-major global) ----
    int hf   = lane >> 5;
    int arow = r0 + wm * 32 + (lane & 31);
    const half8* Ash = (const half8*)A;
    const half8* B1  = (const half8*)Wp1;

    floatx16 acc[4];
#pragma unroll
    for (int nt = 0; nt < 4; ++nt)
#pragma unroll
        for (int i = 0; i < 16; ++i) acc[nt][i] = 0.0f;

#pragma unroll 4
    for (int ks = 0; ks < 16; ++ks) {
        int cb = ks * 2 + hf;   // 16B chunk index within the 256-col row
        half8 a = __builtin_nontemporal_load(
            &Ash[((size_t)(cb >> 2) * MPAD + arow) * 4 + (cb & 3)]);
#pragma unroll
        for (int nt = 0; nt < 4; ++nt) {
            half8 b = B1[(size_t)(ks * 8 + wn * 4 + nt) * 64 + lane];
            acc[nt] = __builtin_amdgcn_mfma_f32_32x32x16_f16(a, b, acc[nt], 0, 0, 0);
        }
    }

    // ---- epilogue 1: t = relu(acc + b1) -> LDS (fp16, swizzled) ----
#pragma unroll
    for (int nt = 0; nt < 4; ++nt) {
        int c  = wn * 128 + nt * 32 + (lane & 31);
        float bv = b1[c];
#pragma unroll
        for (int reg = 0; reg < 16; ++reg) {
            int lr = wm * 32 + (reg & 3) + 8 * (reg >> 2) + 4 * (lane >> 5);
            float v = fmaxf(acc[nt][reg] + bv, 0.0f);
            t_lds[lr * 256 + ((((c >> 3) ^ (lr & 7)) << 3) | (c & 7))] = (_Float16)v;
        }
    }
    __syncthreads();

    // ---- GEMM2: acc2 = t @ W2 (A fragments from swizzled LDS) ----
    const half8* B2 = (const half8*)Wp2;
    int r = wm * 32 + (lane & 31);
    floatx16 acc2[4];
#pragma unroll
    for (int nt = 0; nt < 4; ++nt)
#pragma unroll
        for (int i = 0; i < 16; ++i) acc2[nt][i] = 0.0f;

#pragma unroll 4
    for (int ks = 0; ks < 16; ++ks) {
        int kblk = ks * 2 + (lane >> 5);
        half8 a = *(const half8*)&t_lds[r * 256 + ((kblk ^ (r & 7)) << 3)];
#pragma unroll
        for (int nt = 0; nt < 4; ++nt) {
            half8 b = B2[(size_t)(ks * 8 + wn * 4 + nt) * 64 + lane];
            acc2[nt] = __builtin_amdgcn_mfma_f32_32x32x16_f16(a, b, acc2[nt], 0, 0, 0);
        }
    }

    // ---- epilogue 2: h = relu(acc2 + b2) -> Hout (shard-major) + Fout ----
    const int rbase = wm * 32 + 4 * (lane >> 5);
#pragma unroll
    for (int nt = 0; nt < 4; ++nt) {
        int col = wn * 128 + nt * 32 + (lane & 31);
        float bv = b2[col];
        int shard = wn * 4 + nt;             // col >> 5
#pragma unroll
        for (int reg = 0; reg < 16; ++reg) {
            int rowid = rbase + (reg & 3) + 8 * (reg >> 2);
            int row = r0 + rowid;
            if (row < NN) {
                float v = fmaxf(acc2[nt][reg] + bv, 0.0f);
                if (Hout)
                    __builtin_nontemporal_store(
                        (_Float16)v,
                        &Hout[((size_t)shard * MPAD + row) * 32 + (lane & 31)]);
                __builtin_nontemporal_store(v, &Fout[(size_t)row * 768 + col]);
            }
        }
    }

    // ---- pool accumulate: per-graph column sums (batch sorted; a wave's
    //      32 rows span 1-2 graphs). Cross-half merge by shfl_xor(32),
    //      then one atomicAdd per (graph, col) partial.
    int lastid = NN - 1 - r0 - wm * 32;
    if (lastid >= 0) {
        if (lastid > 31) lastid = 31;
        int g0 = batch_s[wm * 32];
        int g1 = batch_s[wm * 32 + lastid];
        for (int g = g0; g <= g1; ++g) {
#pragma unroll
            for (int nt = 0; nt < 4; ++nt) {
                int col = wn * 128 + nt * 32 + (lane & 31);
                float bv = b2[col];
                float s = 0.0f;
#pragma unroll
                for (int reg = 0; reg < 16; ++reg) {
                    int rowid = rbase + (reg & 3) + 8 * (reg >> 2);
                    if (batch_s[rowid] == g)
                        s += fmaxf(acc2[nt][reg] + bv, 0.0f);
                }
                s += __shfl_xor(s, 32);
                if (lane < 32)
                    atomicAdd(&Gout[(size_t)g * 768 + col], s);
            }
        }
    }
}

// ---------------------------------------------------------------------------
// Finalize pool: graph_embed = gsum / count. One block per graph.
// ---------------------------------------------------------------------------
__global__ void k_pool_final(const float* __restrict__ gsum,
                             const int* __restrict__ batch,
                             float* __restrict__ graph_embed) {
    int g = blockIdx.x;
    int t = threadIdx.x;  // 0..191
    int start, end;
    { int l = 0, h = NN; while (l < h) { int m = (l + h) >> 1; if (batch[m] < g) l = m + 1; else h = m; } start = l; }
    { int l = 0, h = NN; while (l < h) { int m = (l + h) >> 1; if (batch[m] < g + 1) l = m + 1; else h = m; } end = l; }
    int cnt = end - start;
    float inv = 1.0f / (float)(cnt > 0 ? cnt : 1);
    float4 v = ((const float4*)(gsum + (size_t)g * 768))[t];
    float4 o; o.x = v.x * inv; o.y = v.y * inv; o.z = v.z * inv; o.w = v.w * inv;
    ((float4*)(graph_embed + (size_t)g * 768))[t] = o;
}

// ---------------------------------------------------------------------------
extern "C" void kernel_launch(void* const* d_in, const int* in_sizes, int n_in,
                              void* d_out, int out_size, void* d_ws, size_t ws_size,
                              hipStream_t stream) {
    const float* x     = (const float*)d_in[0];  // [N, 256]
    const int*   ei    = (const int*)d_in[1];    // [2, E]
    const int*   batch = (const int*)d_in[2];    // [N] (sorted)
    const float* Ws1   = (const float*)d_in[3];  // [L, 256, 256]
    const float* bs1   = (const float*)d_in[4];  // [L, 256]
    const float* Ws2   = (const float*)d_in[5];  // [L, 256, 256]
    const float* bs2   = (const float*)d_in[6];  // [L, 256]

    float* out         = (float*)d_out;
    float* graph_embed = out;                     // [G, 768]
    float* node_embed  = out + (size_t)GG * 768;  // [N, 768]

    // Workspace (re-poisoned before every call; fully rebuilt here)
    _Float16* h16   = (_Float16*)d_ws;                  // [8][MPAD][32] shard-major
    _Float16* agg16 = h16 + (size_t)MPAD * DD;          // [8][MPAD][32] shard-major
    _Float16* Wp    = agg16 + (size_t)MPAD * DD;        // 6 * 65536 halfs
    float* gsum     = (float*)(Wp + (size_t)6 * 65536); // [G, 768]   (zeroed)
    int* cursor     = (int*)(gsum + (size_t)GG * 768);  // [N] (also deg, zeroed)
    int* bsum       = cursor + NN;                      // [64]       (zeroed)
    int* csr_src    = bsum + 64;                        // [E]
    int* row_ptr    = csr_src + EE;                     // [N+1]

    const int* src = ei;       // edge_index[0]
    const int* dst = ei + EE;  // edge_index[1]

    const int NB = (NN + 1023) / 1024;  // 49 scan blocks

    // Zero gsum + cursor + bsum in one contiguous memset (before k_prep hist!)
    hipMemsetAsync(gsum, 0, (size_t)GG * 768 * 4 + (size_t)NN * 4 + 64 * 4, stream);

    // convert + wpack + hist in one launch
    k_prep<<<CONV_B + WPK_B + HIST_B, 256, 0, stream>>>(x, h16, Ws1, Ws2, Wp, dst, cursor);

    // Finish CSR (dst -> list of src)
    k_scan1<<<NB, 1024, 0, stream>>>(cursor, row_ptr, bsum, NN);
    k_scan2<<<1, 64, 0, stream>>>(bsum, NB, row_ptr + NN);
    k_scan3<<<NB, 1024, 0, stream>>>(row_ptr, bsum, cursor, NN);
    k_scatter<<<(EE + 255) / 256, 256, 0, stream>>>(src, dst, cursor, csr_src, EE);

    for (int l = 0; l < LL; ++l) {
        // agg = h + segment_sum(h[src], dst)  (XCD-sharded)
        k_gather<<<12500 * NSH, 256, 0, stream>>>(h16, row_ptr, csr_src, agg16);
        // h = relu(relu(agg@W1+b1)@W2+b2) -> h16 + node_embed + gsum partials
        k_mlp<<<MPAD / 64, 256, 0, stream>>>(
            agg16, batch,
            Wp + (size_t)(2 * l + 0) * 65536, bs1 + (size_t)l * DD,
            Wp + (size_t)(2 * l + 1) * 65536, bs2 + (size_t)l * DD,
            (l == LL - 1) ? nullptr : h16,
            node_embed + (size_t)l * DD, gsum + (size_t)l * DD);
    }

    k_pool_final<<<GG, 192, 0, stream>>>(gsum, batch, graph_embed);
}

// Round 6
// 709.004 us; speedup vs baseline: 2.0774x; 1.1413x over previous
//
#include <hip/hip_runtime.h>

// Problem constants (match reference setup_inputs)
#define NN 50000
#define EE 800000
#define DD 256
#define LL 3
#define GG 512
#define MPAD 50048   // 782 * 64, GEMM row-tile padding
#define NSH 8        // column shards (one per XCD); 32 cols = 64 B per shard
#define GATHER_GRID (782 * NSH)   // 782 node-groups x 8 shards

typedef __attribute__((ext_vector_type(4))) _Float16 half4;
typedef __attribute__((ext_vector_type(8))) _Float16 half8;
typedef __attribute__((ext_vector_type(16))) float floatx16;
typedef __attribute__((ext_vector_type(4))) int int4v;

// h / agg live in SHARD-MAJOR layout: [shard][MPAD][32] halfs.
// Shard s holds columns [32s, 32s+32). One shard = 3.2 MB < 4 MB XCD L2.

// ---------------------------------------------------------------------------
// Fused prep kernel (independent work, split by blockIdx range):
//   [0, 12500)        : x fp32 -> fp16 convert (into shard-major h)
//   [12500, 12692)    : weight pack (192 blocks)
//   [12692, 15817)    : degree histogram (3125 blocks)
// ---------------------------------------------------------------------------
#define CONV_B 12500
#define WPK_B  192
#define HIST_B 3125

__global__ void k_prep(const float* __restrict__ x, _Float16* __restrict__ h16,
                       const float* __restrict__ Ws1, const float* __restrict__ Ws2,
                       _Float16* __restrict__ Wp,
                       const int* __restrict__ dst, int* __restrict__ deg) {
    int b = blockIdx.x;
    if (b < CONV_B) {
        int i = b * 256 + threadIdx.x;  // float4 groups, NN*64 total
        if (i >= NN * 64) return;
        float4 v = ((const float4*)x)[i];
        half4 o;
        o.x = (_Float16)v.x; o.y = (_Float16)v.y; o.z = (_Float16)v.z; o.w = (_Float16)v.w;
        int r = i >> 6, c4g = i & 63;       // 64 4-col groups per row
        int shard = c4g >> 3, within = c4g & 7;  // 8 groups per 32-col shard
        ((half4*)h16)[((size_t)shard * MPAD + r) * 8 + within] = o;
    } else if (b < CONV_B + WPK_B) {
        // Pre-pack W (fp32 [256,256], k-major) into fp16 MFMA B-fragments for
        // mfma_f32_32x32x16_f16. Fragment (ks,nt): lane l holds
        // B[ks*16 + (l>>5)*8 + j][nt*32 + (l&31)], j=0..7.
        int tid  = (b - CONV_B) * 256 + threadIdx.x;  // 6*16*8*64 = 49152
        int lane = tid & 63;
        int nt   = (tid >> 6) & 7;
        int ks   = (tid >> 9) & 15;
        int w    = tid >> 13;
        if (w >= 6) return;
        int l = w >> 1, s = w & 1;
        const float* W = (s == 0 ? Ws1 : Ws2) + (size_t)l * DD * DD;
        int kbase = ks * 16 + (lane >> 5) * 8;
        int n     = nt * 32 + (lane & 31);
        half8 hi;
#pragma unroll
        for (int j = 0; j < 8; ++j) hi[j] = (_Float16)W[(size_t)(kbase + j) * DD + n];
        ((half8*)Wp)[(((size_t)w * 16 + ks) * 8 + nt) * 64 + lane] = hi;
    } else {
        int i = (b - CONV_B - WPK_B) * 256 + threadIdx.x;
        if (i < EE) atomicAdd(&deg[dst[i]], 1);
    }
}

// ---------------------------------------------------------------------------
// CSR build: 3-kernel parallel scan -> scatter (histogram is in k_prep)
// ---------------------------------------------------------------------------
__global__ void k_scan1(const int* __restrict__ deg, int* __restrict__ rp,
                        int* __restrict__ bsum, int n) {
    __shared__ int s[1024];
    int t = threadIdx.x;
    int i = blockIdx.x * 1024 + t;
    int v = (i < n) ? deg[i] : 0;
    s[t] = v;
    __syncthreads();
    for (int off = 1; off < 1024; off <<= 1) {
        int tmp = (t >= off) ? s[t - off] : 0;
        __syncthreads();
        s[t] += tmp;
        __syncthreads();
    }
    if (i < n) rp[i] = s[t] - v;          // local exclusive
    if (t == 1023) bsum[blockIdx.x] = s[1023];
}

__global__ void k_scan2(int* __restrict__ bsum, int nb, int* __restrict__ total_out) {
    int lane = threadIdx.x & 63;
    int v = (lane < nb) ? bsum[lane] : 0;
    int orig = v;
    for (int off = 1; off < 64; off <<= 1) {
        int u = __shfl_up(v, off);
        if (lane >= off) v += u;
    }
    if (lane < nb) bsum[lane] = v - orig;  // exclusive block offsets
    if (lane == 63) *total_out = v;        // grand total -> row_ptr[N]
}

__global__ void k_scan3(int* __restrict__ rp, const int* __restrict__ bsum,
                        int* __restrict__ cursor, int n) {
    int i = blockIdx.x * 1024 + threadIdx.x;
    if (i < n) {
        int v = rp[i] + bsum[blockIdx.x];
        rp[i] = v;
        cursor[i] = v;
    }
}

__global__ void k_scatter(const int* __restrict__ src, const int* __restrict__ dst,
                          int* __restrict__ cursor, int* __restrict__ csr_src, int e) {
    int i = blockIdx.x * blockDim.x + threadIdx.x;
    if (i < e) {
        int d = dst[i];
        int pos = atomicAdd(&cursor[d], 1);
        csr_src[pos] = src[i];
    }
}

// ---------------------------------------------------------------------------
// XCD-sharded aggregation, lane-sequential form: agg[n] = h[n] + sum h[j].
// Shard = blockIdx & 7 -> consecutive blocks round-robin across XCDs, so
// shard k's 3.2 MB h slice stays resident in XCD k's 4 MB L2 (round 5
// verified: gather FETCH_SIZE 185 -> 26 MB).
// Round-6 restructure (round 5 was VALU/issue-bound at 48% VALUBusy):
//   - 4 lanes per node x 16 nodes per wave; lane owns one 16 B part of its
//     node's 64 B shard row and accumulates SEQUENTIALLY over the edge list.
//     NO cross-lane reduce (round 5 paid a 5-round shuffle tree per node).
//   - 8-deep two-pass batches: 8 index loads (one wait), 8 row loads (one
//     wait), 8 pk-adds -> ~3 instructions per 16 edge-visits.
//   - waves: 400K -> 25K; no LDS; modest VGPR -> high occupancy.
// csr_src read nontemporal (no L2 allocate, protects h residency); agg
// written nontemporal (single-use stream, consumed by mlp from HBM).
// ---------------------------------------------------------------------------
__global__ __launch_bounds__(256) void k_gather(
        const _Float16* __restrict__ h,
        const int* __restrict__ row_ptr,
        const int* __restrict__ csr_src,
        _Float16* __restrict__ agg) {
    int t = threadIdx.x, lane = t & 63, w = t >> 6;
    int shard = blockIdx.x & 7;
    int grp   = blockIdx.x >> 3;           // 782 groups of 64 nodes
    int nsub  = lane >> 2;                 // 16 nodes per wave
    int part  = lane & 3;                  // 16 B part within 64 B shard row
    int n = grp * 64 + w * 16 + nsub;
    const half8* hp8 = (const half8*)h;
    size_t sbase = (size_t)shard * MPAD;

    int beg = 0, end = 0;
    if (n < NN) { beg = row_ptr[n]; end = row_ptr[n + 1]; }

    half8 acc;
#pragma unroll
    for (int i = 0; i < 8; ++i) acc[i] = (_Float16)0;
    if (n < NN) acc = hp8[(sbase + n) * 4 + part];   // self row

    int j = beg;
    while (__any(j < end)) {
        // pass 1: 8 independent index loads (4 lanes/node coalesce to one)
        int idx[8];
#pragma unroll
        for (int u = 0; u < 8; ++u) {
            int e = j + u;
            idx[u] = (e < end) ? __builtin_nontemporal_load(&csr_src[e]) : -1;
        }
        // pass 2: 8 independent row loads (predicated), then accumulate
        half8 v[8];
#pragma unroll
        for (int u = 0; u < 8; ++u) {
#pragma unroll
            for (int i = 0; i < 8; ++i) v[u][i] = (_Float16)0;
            if (idx[u] >= 0) v[u] = hp8[(sbase + idx[u]) * 4 + part];
        }
#pragma unroll
        for (int u = 0; u < 8; ++u) acc += v[u];
        j += 8;
    }

    if (n < NN)
        __builtin_nontemporal_store(*(int4v*)&acc,
                                    (int4v*)agg + (sbase + n) * 4 + part);
}

// ---------------------------------------------------------------------------
// Fused MLP + pool-accumulate: h_out = relu(relu(A@W1+b1)@W2+b2).
// Block: 256 threads = 4 waves, 64-row x 256-col tile; wave (wm,wn) owns the
// 32-row x 128-col quadrant (4 n-tiles of mfma_f32_32x32x16_f16).
// A (agg, shard-major) read with REGULAR loads (round 5's nt loads exposed
// raw HBM latency; allocating loads stream at full BW). t round-trips
// through LDS fp16 with XOR swizzle. Hout (shard-major) and Fout
// (node_embed) written nontemporal -- single-use streams, keep L2 clean.
// Hout == nullptr on the last layer (never read).
// ---------------------------------------------------------------------------
__global__ __launch_bounds__(256) void k_mlp(
        const _Float16* __restrict__ A,    // agg16 shard-major
        const int* __restrict__ batch,
        const _Float16* __restrict__ Wp1, const float* __restrict__ b1,
        const _Float16* __restrict__ Wp2, const float* __restrict__ b2,
        _Float16* __restrict__ Hout,       // h16 shard-major (or nullptr)
        float* __restrict__ Fout,          // node_embed + l*256, row stride 768
        float* __restrict__ Gout) {        // gsum + l*256, row stride 768
    __shared__ _Float16 t_lds[64 * 256];   // 32 KB
    __shared__ int batch_s[64];
    int t    = threadIdx.x;
    int lane = t & 63;
    int w    = t >> 6;
    int wm   = w >> 1, wn = w & 1;
    int r0   = blockIdx.x * 64;

    if (t < 64) {
        int r = r0 + t;
        batch_s[t] = (r < NN) ? batch[r] : 0x7fffffff;
    }

    // ---- GEMM1: acc = A @ W1 (A fragments from shard-major global) ----
    int hf   = lane >> 5;
    int arow = r0 + wm * 32 + (lane & 31);
    const half8* Ash = (const half8*)A;
    const half8* B1  = (const half8*)Wp1;

    floatx16 acc[4];
#pragma unroll
    for (int nt = 0; nt < 4; ++nt)
#pragma unroll
        for (int i = 0; i < 16; ++i) acc[nt][i] = 0.0f;

#pragma unroll 4
    for (int ks = 0; ks < 16; ++ks) {
        int cb = ks * 2 + hf;   // 16B chunk index within the 256-col row
        half8 a = Ash[((size_t)(cb >> 2) * MPAD + arow) * 4 + (cb & 3)];
#pragma unroll
        for (int nt = 0; nt < 4; ++nt) {
            half8 b = B1[(size_t)(ks * 8 + wn * 4 + nt) * 64 + lane];
            acc[nt] = __builtin_amdgcn_mfma_f32_32x32x16_f16(a, b, acc[nt], 0, 0, 0);
        }
    }

    // ---- epilogue 1: t = relu(acc + b1) -> LDS (fp16, swizzled) ----
#pragma unroll
    for (int nt = 0; nt < 4; ++nt) {
        int c  = wn * 128 + nt * 32 + (lane & 31);
        float bv = b1[c];
#pragma unroll
        for (int reg = 0; reg < 16; ++reg) {
            int lr = wm * 32 + (reg & 3) + 8 * (reg >> 2) + 4 * (lane >> 5);
            float v = fmaxf(acc[nt][reg] + bv, 0.0f);
            t_lds[lr * 256 + ((((c >> 3) ^ (lr & 7)) << 3) | (c & 7))] = (_Float16)v;
        }
    }
    __syncthreads();

    // ---- GEMM2: acc2 = t @ W2 (A fragments from swizzled LDS) ----
    const half8* B2 = (const half8*)Wp2;
    int r = wm * 32 + (lane & 31);
    floatx16 acc2[4];
#pragma unroll
    for (int nt = 0; nt < 4; ++nt)
#pragma unroll
        for (int i = 0; i < 16; ++i) acc2[nt][i] = 0.0f;

#pragma unroll 4
    for (int ks = 0; ks < 16; ++ks) {
        int kblk = ks * 2 + (lane >> 5);
        half8 a = *(const half8*)&t_lds[r * 256 + ((kblk ^ (r & 7)) << 3)];
#pragma unroll
        for (int nt = 0; nt < 4; ++nt) {
            half8 b = B2[(size_t)(ks * 8 + wn * 4 + nt) * 64 + lane];
            acc2[nt] = __builtin_amdgcn_mfma_f32_32x32x16_f16(a, b, acc2[nt], 0, 0, 0);
        }
    }

    // ---- epilogue 2: h = relu(acc2 + b2) -> Hout (shard-major) + Fout ----
    const int rbase = wm * 32 + 4 * (lane >> 5);
#pragma unroll
    for (int nt = 0; nt < 4; ++nt) {
        int col = wn * 128 + nt * 32 + (lane & 31);
        float bv = b2[col];
        int shard = wn * 4 + nt;             // col >> 5
#pragma unroll
        for (int reg = 0; reg < 16; ++reg) {
            int rowid = rbase + (reg & 3) + 8 * (reg >> 2);
            int row = r0 + rowid;
            if (row < NN) {
                float v = fmaxf(acc2[nt][reg] + bv, 0.0f);
                if (Hout)
                    __builtin_nontemporal_store(
                        (_Float16)v,
                        &Hout[((size_t)shard * MPAD + row) * 32 + (lane & 31)]);
                __builtin_nontemporal_store(v, &Fout[(size_t)row * 768 + col]);
            }
        }
    }

    // ---- pool accumulate: per-graph column sums (batch sorted; a wave's
    //      32 rows span 1-2 graphs). Cross-half merge by shfl_xor(32),
    //      then one atomicAdd per (graph, col) partial.
    int lastid = NN - 1 - r0 - wm * 32;
    if (lastid >= 0) {
        if (lastid > 31) lastid = 31;
        int g0 = batch_s[wm * 32];
        int g1 = batch_s[wm * 32 + lastid];
        for (int g = g0; g <= g1; ++g) {
#pragma unroll
            for (int nt = 0; nt < 4; ++nt) {
                int col = wn * 128 + nt * 32 + (lane & 31);
                float bv = b2[col];
                float s = 0.0f;
#pragma unroll
                for (int reg = 0; reg < 16; ++reg) {
                    int rowid = rbase + (reg & 3) + 8 * (reg >> 2);
                    if (batch_s[rowid] == g)
                        s += fmaxf(acc2[nt][reg] + bv, 0.0f);
                }
                s += __shfl_xor(s, 32);
                if (lane < 32)
                    atomicAdd(&Gout[(size_t)g * 768 + col], s);
            }
        }
    }
}

// ---------------------------------------------------------------------------
// Finalize pool: graph_embed = gsum / count. One block per graph.
// ---------------------------------------------------------------------------
__global__ void k_pool_final(const float* __restrict__ gsum,
                             const int* __restrict__ batch,
                             float* __restrict__ graph_embed) {
    int g = blockIdx.x;
    int t = threadIdx.x;  // 0..191
    int start, end;
    { int l = 0, h = NN; while (l < h) { int m = (l + h) >> 1; if (batch[m] < g) l = m + 1; else h = m; } start = l; }
    { int l = 0, h = NN; while (l < h) { int m = (l + h) >> 1; if (batch[m] < g + 1) l = m + 1; else h = m; } end = l; }
    int cnt = end - start;
    float inv = 1.0f / (float)(cnt > 0 ? cnt : 1);
    float4 v = ((const float4*)(gsum + (size_t)g * 768))[t];
    float4 o; o.x = v.x * inv; o.y = v.y * inv; o.z = v.z * inv; o.w = v.w * inv;
    ((float4*)(graph_embed + (size_t)g * 768))[t] = o;
}

// ---------------------------------------------------------------------------
extern "C" void kernel_launch(void* const* d_in, const int* in_sizes, int n_in,
                              void* d_out, int out_size, void* d_ws, size_t ws_size,
                              hipStream_t stream) {
    const float* x     = (const float*)d_in[0];  // [N, 256]
    const int*   ei    = (const int*)d_in[1];    // [2, E]
    const int*   batch = (const int*)d_in[2];    // [N] (sorted)
    const float* Ws1   = (const float*)d_in[3];  // [L, 256, 256]
    const float* bs1   = (const float*)d_in[4];  // [L, 256]
    const float* Ws2   = (const float*)d_in[5];  // [L, 256, 256]
    const float* bs2   = (const float*)d_in[6];  // [L, 256]

    float* out         = (float*)d_out;
    float* graph_embed = out;                     // [G, 768]
    float* node_embed  = out + (size_t)GG * 768;  // [N, 768]

    // Workspace (re-poisoned before every call; fully rebuilt here)
    _Float16* h16   = (_Float16*)d_ws;                  // [8][MPAD][32] shard-major
    _Float16* agg16 = h16 + (size_t)MPAD * DD;          // [8][MPAD][32] shard-major
    _Float16* Wp    = agg16 + (size_t)MPAD * DD;        // 6 * 65536 halfs
    float* gsum     = (float*)(Wp + (size_t)6 * 65536); // [G, 768]   (zeroed)
    int* cursor     = (int*)(gsum + (size_t)GG * 768);  // [N] (also deg, zeroed)
    int* bsum       = cursor + NN;                      // [64]       (zeroed)
    int* csr_src    = bsum + 64;                        // [E]
    int* row_ptr    = csr_src + EE;                     // [N+1]

    const int* src = ei;       // edge_index[0]
    const int* dst = ei + EE;  // edge_index[1]

    const int NB = (NN + 1023) / 1024;  // 49 scan blocks

    // Zero gsum + cursor + bsum in one contiguous memset (before k_prep hist!)
    hipMemsetAsync(gsum, 0, (size_t)GG * 768 * 4 + (size_t)NN * 4 + 64 * 4, stream);

    // convert + wpack + hist in one launch
    k_prep<<<CONV_B + WPK_B + HIST_B, 256, 0, stream>>>(x, h16, Ws1, Ws2, Wp, dst, cursor);

    // Finish CSR (dst -> list of src)
    k_scan1<<<NB, 1024, 0, stream>>>(cursor, row_ptr, bsum, NN);
    k_scan2<<<1, 64, 0, stream>>>(bsum, NB, row_ptr + NN);
    k_scan3<<<NB, 1024, 0, stream>>>(row_ptr, bsum, cursor, NN);
    k_scatter<<<(EE + 255) / 256, 256, 0, stream>>>(src, dst, cursor, csr_src, EE);

    for (int l = 0; l < LL; ++l) {
        // agg = h + segment_sum(h[src], dst)  (XCD-sharded, lane-sequential)
        k_gather<<<GATHER_GRID, 256, 0, stream>>>(h16, row_ptr, csr_src, agg16);
        // h = relu(relu(agg@W1+b1)@W2+b2) -> h16 + node_embed + gsum partials
        k_mlp<<<MPAD / 64, 256, 0, stream>>>(
            agg16, batch,
            Wp + (size_t)(2 * l + 0) * 65536, bs1 + (size_t)l * DD,
            Wp + (size_t)(2 * l + 1) * 65536, bs2 + (size_t)l * DD,
            (l == LL - 1) ? nullptr : h16,
            node_embed + (size_t)l * DD, gsum + (size_t)l * DD);
    }

    k_pool_final<<<GG, 192, 0, stream>>>(gsum, batch, graph_embed);
}

// Round 7
// 594.771 us; speedup vs baseline: 2.4764x; 1.1921x over previous
//
#include <hip/hip_runtime.h>

// Problem constants (match reference setup_inputs)
#define NN 50000
#define EE 800000
#define DD 256
#define LL 3
#define GG 512
#define MPAD 50048   // 1564 * 32, GEMM row-tile padding

typedef __attribute__((ext_vector_type(4))) _Float16 half4;
typedef __attribute__((ext_vector_type(8))) _Float16 half8;
typedef __attribute__((ext_vector_type(16))) float floatx16;

// ---------------------------------------------------------------------------
// Fused prep kernel (independent work, split by blockIdx range):
//   [0, 12500)        : x fp32 -> fp16 convert (row-major h)
//   [12500, 12692)    : weight pack (192 blocks)
//   [12692, 15817)    : degree histogram (3125 blocks)
// ---------------------------------------------------------------------------
#define CONV_B 12500
#define WPK_B  192
#define HIST_B 3125

__global__ void k_prep(const float* __restrict__ x, _Float16* __restrict__ h16,
                       const float* __restrict__ Ws1, const float* __restrict__ Ws2,
                       _Float16* __restrict__ Wp,
                       const int* __restrict__ dst, int* __restrict__ deg) {
    int b = blockIdx.x;
    if (b < CONV_B) {
        int i = b * 256 + threadIdx.x;  // float4 groups, NN*DD/4 = 3.2M
        if (i >= NN * DD / 4) return;
        float4 v = ((const float4*)x)[i];
        half4 o;
        o.x = (_Float16)v.x; o.y = (_Float16)v.y; o.z = (_Float16)v.z; o.w = (_Float16)v.w;
        ((half4*)h16)[i] = o;
    } else if (b < CONV_B + WPK_B) {
        // Pre-pack W (fp32 [256,256], k-major) into fp16 MFMA B-fragments for
        // mfma_f32_32x32x16_f16. Fragment (ks,nb): lane l holds
        // B[ks*16 + (l>>5)*8 + j][nb*32 + (l&31)], j=0..7.
        int tid  = (b - CONV_B) * 256 + threadIdx.x;  // 6*16*8*64 = 49152
        int lane = tid & 63;
        int nb   = (tid >> 6) & 7;
        int ks   = (tid >> 9) & 15;
        int w    = tid >> 13;
        if (w >= 6) return;
        int l = w >> 1, s = w & 1;
        const float* W = (s == 0 ? Ws1 : Ws2) + (size_t)l * DD * DD;
        int kbase = ks * 16 + (lane >> 5) * 8;
        int n     = nb * 32 + (lane & 31);
        half8 hi;
#pragma unroll
        for (int j = 0; j < 8; ++j) hi[j] = (_Float16)W[(size_t)(kbase + j) * DD + n];
        ((half8*)Wp)[(((size_t)w * 16 + ks) * 8 + nb) * 64 + lane] = hi;
    } else {
        int i = (b - CONV_B - WPK_B) * 256 + threadIdx.x;
        if (i < EE) atomicAdd(&deg[dst[i]], 1);
    }
}

// ---------------------------------------------------------------------------
// CSR build: 3-kernel parallel scan -> scatter (histogram is in k_prep)
// ---------------------------------------------------------------------------
__global__ void k_scan1(const int* __restrict__ deg, int* __restrict__ rp,
                        int* __restrict__ bsum, int n) {
    __shared__ int s[1024];
    int t = threadIdx.x;
    int i = blockIdx.x * 1024 + t;
    int v = (i < n) ? deg[i] : 0;
    s[t] = v;
    __syncthreads();
    for (int off = 1; off < 1024; off <<= 1) {
        int tmp = (t >= off) ? s[t - off] : 0;
        __syncthreads();
        s[t] += tmp;
        __syncthreads();
    }
    if (i < n) rp[i] = s[t] - v;          // local exclusive
    if (t == 1023) bsum[blockIdx.x] = s[1023];
}

__global__ void k_scan2(int* __restrict__ bsum, int nb, int* __restrict__ total_out) {
    int lane = threadIdx.x & 63;
    int v = (lane < nb) ? bsum[lane] : 0;
    int orig = v;
    for (int off = 1; off < 64; off <<= 1) {
        int u = __shfl_up(v, off);
        if (lane >= off) v += u;
    }
    if (lane < nb) bsum[lane] = v - orig;  // exclusive block offsets
    if (lane == 63) *total_out = v;        // grand total -> row_ptr[N]
}

__global__ void k_scan3(int* __restrict__ rp, const int* __restrict__ bsum,
                        int* __restrict__ cursor, int n) {
    int i = blockIdx.x * 1024 + threadIdx.x;
    if (i < n) {
        int v = rp[i] + bsum[blockIdx.x];
        rp[i] = v;
        cursor[i] = v;
    }
}

__global__ void k_scatter(const int* __restrict__ src, const int* __restrict__ dst,
                          int* __restrict__ cursor, int* __restrict__ csr_src, int e) {
    int i = blockIdx.x * blockDim.x + threadIdx.x;
    if (i < e) {
        int d = dst[i];
        int pos = atomicAdd(&cursor[d], 1);
        csr_src[pos] = src[i];
    }
}

// ---------------------------------------------------------------------------
// Aggregation (round-3 form, best measured): agg[n] = h[n] + sum_{j->n} h[j].
// One wave per node, 4 nodes per 256-thread block.
//   - half8 (16 B/lane) row loads: 32 lanes fetch a full 512 B row; lanes
//     0-31 take even-indexed edges, lanes 32-63 odd.
//   - 8 loads in flight = 16 edges/batch; predicated static-indexed tail.
//   - block's CSR segment staged in LDS first (no dependent global index
//     loads on the row critical path).
// Final cross-half fold via shfl_xor(32); lanes 0-31 store the row.
// ---------------------------------------------------------------------------
__global__ __launch_bounds__(256) void k_gather(
        const _Float16* __restrict__ h,
        const int* __restrict__ row_ptr,
        const int* __restrict__ csr_src,
        _Float16* __restrict__ agg) {
    __shared__ int eidx[1024];
    __shared__ int rp_s[5];
    int t = threadIdx.x, lane = t & 63, w = t >> 6;
    int n0 = blockIdx.x * 4;
    if (t < 5) {
        int nn = n0 + t;
        if (nn > NN) nn = NN;
        rp_s[t] = row_ptr[nn];
    }
    __syncthreads();
    int beg0 = rp_s[0];
    int cnt  = rp_s[4] - beg0;
    for (int i = t; i < cnt && i < 1024; i += 256) eidx[i] = csr_src[beg0 + i];
    __syncthreads();

    int n = n0 + w;
    if (n >= NN) return;
    int beg = rp_s[w] - beg0, end = rp_s[w + 1] - beg0;
    int hf = lane >> 5;   // 0: own row + even edges; 1: odd edges
    int cl = lane & 31;   // column group: cols [cl*8, cl*8+8)
    const half8* hp = (const half8*)h;  // row n = hp[n*32 + cl]

    half8 acc;
#pragma unroll
    for (int i = 0; i < 8; ++i) acc[i] = (_Float16)0;
    if (hf == 0) acc = hp[(size_t)n * 32 + cl];

    if (cnt <= 1024) {
        int k = beg;
        for (; k + 16 <= end; k += 16) {
            half8 v[8];
#pragma unroll
            for (int u = 0; u < 8; ++u) {
                int s = eidx[k + 2 * u + hf];
                v[u] = hp[(size_t)s * 32 + cl];
            }
#pragma unroll
            for (int u = 0; u < 8; ++u) acc += v[u];
        }
        if (k < end) {  // tail < 16 edges: predicated, all loads in flight
#pragma unroll
            for (int u = 0; u < 8; ++u) {
                int e = k + 2 * u + hf;
                half8 v;
#pragma unroll
                for (int i = 0; i < 8; ++i) v[i] = (_Float16)0;
                if (e < end) v = hp[(size_t)eidx[e] * 32 + cl];
                acc += v;
            }
        }
    } else {
        // rare fallback: indices from global
        int k = beg;
        for (; k + 16 <= end; k += 16) {
            half8 v[8];
#pragma unroll
            for (int u = 0; u < 8; ++u) {
                int s = csr_src[beg0 + k + 2 * u + hf];
                v[u] = hp[(size_t)s * 32 + cl];
            }
#pragma unroll
            for (int u = 0; u < 8; ++u) acc += v[u];
        }
        if (k < end) {
#pragma unroll
            for (int u = 0; u < 8; ++u) {
                int e = k + 2 * u + hf;
                half8 v;
#pragma unroll
                for (int i = 0; i < 8; ++i) v[i] = (_Float16)0;
                if (e < end) v = hp[(size_t)csr_src[beg0 + e] * 32 + cl];
                acc += v;
            }
        }
    }

    // fold odd-half into even-half (16 B = int4 via 4 shfl_xor)
    int4 ai = *(int4*)&acc;
    int4 bi;
    bi.x = __shfl_xor(ai.x, 32);
    bi.y = __shfl_xor(ai.y, 32);
    bi.z = __shfl_xor(ai.z, 32);
    bi.w = __shfl_xor(ai.w, 32);
    acc += *(half8*)&bi;
    if (hf == 0) ((half8*)(agg + (size_t)n * DD))[cl] = acc;
}

// ---------------------------------------------------------------------------
// Fused MLP + pool-accumulate: h_out = relu(relu(A@W1+b1)@W2+b2).
// Round-7 re-tile for occupancy (mlp was latency-bound at 782 blocks /
// 12.2 waves/CU, ~5x above its ~20 us roofline):
//   Block: 256 threads = 4 waves covering a 32-row x 256-col tile; wave w
//   owns 32 rows x 64 cols = 2 n-tiles of mfma_f32_32x32x16_f16.
//   Grid: 1564 blocks -> 24.4 waves/CU resident (2x round-3), LDS 16.5 KB,
//   acc VGPRs halved. Same total loads/MFMAs, double latency hiding.
// GEMM1 A direct from global; t round-trips through swizzled fp16 LDS.
// Hout regular store (next gather reads it); skipped on last layer.
// Fout nontemporal (never re-read).
// ---------------------------------------------------------------------------
__global__ __launch_bounds__(256) void k_mlp(
        const _Float16* __restrict__ A,    // agg16 [MPAD, 256]
        const int* __restrict__ batch,
        const _Float16* __restrict__ Wp1, const float* __restrict__ b1,
        const _Float16* __restrict__ Wp2, const float* __restrict__ b2,
        _Float16* __restrict__ Hout,       // h16 [MPAD, 256] (or nullptr)
        float* __restrict__ Fout,          // node_embed + l*256, row stride 768
        float* __restrict__ Gout) {        // gsum + l*256, row stride 768
    __shared__ _Float16 t_lds[32 * 256];   // 16 KB
    __shared__ int batch_s[32];
    int t    = threadIdx.x;
    int lane = t & 63;
    int w    = t >> 6;                     // wave = n-quadrant [w*64, w*64+64)
    int r0   = blockIdx.x * 32;

    if (t < 32) {
        int r = r0 + t;
        batch_s[t] = (r < NN) ? batch[r] : 0x7fffffff;
    }

    // ---- GEMM1: acc = A @ W1 (A fragments direct from global) ----
    int arow = r0 + (lane & 31);
    const half8* baseA = (const half8*)(A + (size_t)arow * DD) + (lane >> 5);
    const half8* B1    = (const half8*)Wp1;

    floatx16 acc[2];
#pragma unroll
    for (int nt = 0; nt < 2; ++nt)
#pragma unroll
        for (int i = 0; i < 16; ++i) acc[nt][i] = 0.0f;

#pragma unroll 4
    for (int ks = 0; ks < 16; ++ks) {
        half8 a = baseA[ks * 2];
#pragma unroll
        for (int nt = 0; nt < 2; ++nt) {
            half8 b = B1[(size_t)(ks * 8 + w * 2 + nt) * 64 + lane];
            acc[nt] = __builtin_amdgcn_mfma_f32_32x32x16_f16(a, b, acc[nt], 0, 0, 0);
        }
    }

    // ---- epilogue 1: t = relu(acc + b1) -> LDS (fp16, swizzled) ----
#pragma unroll
    for (int nt = 0; nt < 2; ++nt) {
        int c  = w * 64 + nt * 32 + (lane & 31);
        float bv = b1[c];
#pragma unroll
        for (int reg = 0; reg < 16; ++reg) {
            int lr = (reg & 3) + 8 * (reg >> 2) + 4 * (lane >> 5);  // 0..31
            float v = fmaxf(acc[nt][reg] + bv, 0.0f);
            t_lds[lr * 256 + ((((c >> 3) ^ (lr & 7)) << 3) | (c & 7))] = (_Float16)v;
        }
    }
    __syncthreads();

    // ---- GEMM2: acc2 = t @ W2 (A fragments from swizzled LDS) ----
    const half8* B2 = (const half8*)Wp2;
    int r = lane & 31;
    floatx16 acc2[2];
#pragma unroll
    for (int nt = 0; nt < 2; ++nt)
#pragma unroll
        for (int i = 0; i < 16; ++i) acc2[nt][i] = 0.0f;

#pragma unroll 4
    for (int ks = 0; ks < 16; ++ks) {
        int kblk = ks * 2 + (lane >> 5);
        half8 a = *(const half8*)&t_lds[r * 256 + ((kblk ^ (r & 7)) << 3)];
#pragma unroll
        for (int nt = 0; nt < 2; ++nt) {
            half8 b = B2[(size_t)(ks * 8 + w * 2 + nt) * 64 + lane];
            acc2[nt] = __builtin_amdgcn_mfma_f32_32x32x16_f16(a, b, acc2[nt], 0, 0, 0);
        }
    }

    // ---- epilogue 2: h = relu(acc2 + b2) -> fp16 Hout + fp32 node_embed ----
    const int rbase = 4 * (lane >> 5);
#pragma unroll
    for (int nt = 0; nt < 2; ++nt) {
        int col = w * 64 + nt * 32 + (lane & 31);
        float bv = b2[col];
#pragma unroll
        for (int reg = 0; reg < 16; ++reg) {
            int rowid = rbase + (reg & 3) + 8 * (reg >> 2);   // 0..31
            int row = r0 + rowid;
            if (row < NN) {
                float v = fmaxf(acc2[nt][reg] + bv, 0.0f);
                if (Hout) Hout[(size_t)row * DD + col] = (_Float16)v;
                __builtin_nontemporal_store(v, &Fout[(size_t)row * 768 + col]);
            }
        }
    }

    // ---- pool accumulate: per-graph column sums (batch sorted; the tile's
    //      32 rows span 1-2 graphs). Cross-half merge by shfl_xor(32),
    //      then one atomicAdd per (graph, col) partial.
    int lastid = NN - 1 - r0;
    if (lastid >= 0) {
        if (lastid > 31) lastid = 31;
        int g0 = batch_s[0];
        int g1 = batch_s[lastid];
        for (int g = g0; g <= g1; ++g) {
#pragma unroll
            for (int nt = 0; nt < 2; ++nt) {
                int col = w * 64 + nt * 32 + (lane & 31);
                float bv = b2[col];
                float s = 0.0f;
#pragma unroll
                for (int reg = 0; reg < 16; ++reg) {
                    int rowid = rbase + (reg & 3) + 8 * (reg >> 2);
                    if (batch_s[rowid] == g)
                        s += fmaxf(acc2[nt][reg] + bv, 0.0f);
                }
                s += __shfl_xor(s, 32);
                if (lane < 32)
                    atomicAdd(&Gout[(size_t)g * 768 + col], s);
            }
        }
    }
}

// ---------------------------------------------------------------------------
// Finalize pool: graph_embed = gsum / count. One block per graph.
// ---------------------------------------------------------------------------
__global__ void k_pool_final(const float* __restrict__ gsum,
                             const int* __restrict__ batch,
                             float* __restrict__ graph_embed) {
    int g = blockIdx.x;
    int t = threadIdx.x;  // 0..191
    int start, end;
    { int l = 0, h = NN; while (l < h) { int m = (l + h) >> 1; if (batch[m] < g) l = m + 1; else h = m; } start = l; }
    { int l = 0, h = NN; while (l < h) { int m = (l + h) >> 1; if (batch[m] < g + 1) l = m + 1; else h = m; } end = l; }
    int cnt = end - start;
    float inv = 1.0f / (float)(cnt > 0 ? cnt : 1);
    float4 v = ((const float4*)(gsum + (size_t)g * 768))[t];
    float4 o; o.x = v.x * inv; o.y = v.y * inv; o.z = v.z * inv; o.w = v.w * inv;
    ((float4*)(graph_embed + (size_t)g * 768))[t] = o;
}

// ---------------------------------------------------------------------------
extern "C" void kernel_launch(void* const* d_in, const int* in_sizes, int n_in,
                              void* d_out, int out_size, void* d_ws, size_t ws_size,
                              hipStream_t stream) {
    const float* x     = (const float*)d_in[0];  // [N, 256]
    const int*   ei    = (const int*)d_in[1];    // [2, E]
    const int*   batch = (const int*)d_in[2];    // [N] (sorted)
    const float* Ws1   = (const float*)d_in[3];  // [L, 256, 256]
    const float* bs1   = (const float*)d_in[4];  // [L, 256]
    const float* Ws2   = (const float*)d_in[5];  // [L, 256, 256]
    const float* bs2   = (const float*)d_in[6];  // [L, 256]

    float* out         = (float*)d_out;
    float* graph_embed = out;                     // [G, 768]
    float* node_embed  = out + (size_t)GG * 768;  // [N, 768]

    // Workspace (re-poisoned before every call; fully rebuilt here)
    _Float16* h16   = (_Float16*)d_ws;                  // [MPAD, 256]
    _Float16* agg16 = h16 + (size_t)MPAD * DD;          // [MPAD, 256]
    _Float16* Wp    = agg16 + (size_t)MPAD * DD;        // 6 * 65536 halfs
    float* gsum     = (float*)(Wp + (size_t)6 * 65536); // [G, 768]   (zeroed)
    int* cursor     = (int*)(gsum + (size_t)GG * 768);  // [N] (also deg, zeroed)
    int* bsum       = cursor + NN;                      // [64]       (zeroed)
    int* csr_src    = bsum + 64;                        // [E]
    int* row_ptr    = csr_src + EE;                     // [N+1]

    const int* src = ei;       // edge_index[0]
    const int* dst = ei + EE;  // edge_index[1]

    const int NB = (NN + 1023) / 1024;  // 49 scan blocks

    // Zero gsum + cursor + bsum in one contiguous memset (before k_prep hist!)
    hipMemsetAsync(gsum, 0, (size_t)GG * 768 * 4 + (size_t)NN * 4 + 64 * 4, stream);

    // convert + wpack + hist in one launch
    k_prep<<<CONV_B + WPK_B + HIST_B, 256, 0, stream>>>(x, h16, Ws1, Ws2, Wp, dst, cursor);

    // Finish CSR (dst -> list of src)
    k_scan1<<<NB, 1024, 0, stream>>>(cursor, row_ptr, bsum, NN);
    k_scan2<<<1, 64, 0, stream>>>(bsum, NB, row_ptr + NN);
    k_scan3<<<NB, 1024, 0, stream>>>(row_ptr, bsum, cursor, NN);
    k_scatter<<<(EE + 255) / 256, 256, 0, stream>>>(src, dst, cursor, csr_src, EE);

    for (int l = 0; l < LL; ++l) {
        // agg = h + segment_sum(h[src], dst)
        k_gather<<<(NN + 3) / 4, 256, 0, stream>>>(h16, row_ptr, csr_src, agg16);
        // h = relu(relu(agg@W1+b1)@W2+b2) -> h16 + node_embed + gsum partials
        k_mlp<<<MPAD / 32, 256, 0, stream>>>(
            agg16, batch,
            Wp + (size_t)(2 * l + 0) * 65536, bs1 + (size_t)l * DD,
            Wp + (size_t)(2 * l + 1) * 65536, bs2 + (size_t)l * DD,
            (l == LL - 1) ? nullptr : h16,
            node_embed + (size_t)l * DD, gsum + (size_t)l * DD);
    }

    k_pool_final<<<GG, 192, 0, stream>>>(gsum, batch, graph_embed);
}